// Round 1
// baseline (282.025 us; speedup 1.0000x reference)
//
#include <hip/hip_runtime.h>

typedef __attribute__((ext_vector_type(8))) short short8v;
typedef __attribute__((ext_vector_type(4))) float floatx4;

#define S_LEN 1024
#define DMODEL 1024
#define NH 16
#define DK 64
#define NB_TAB 2047  // rel = k - q in [-1023, 1023]

__device__ __forceinline__ short f2bf(float f) {
  unsigned u = __builtin_bit_cast(unsigned, f);
  u += 0x7fffu + ((u >> 16) & 1u);  // RNE
  return (short)(u >> 16);
}

// out[n][k] = bf16(in[k][n]), 1024x1024. block (32,8), grid (32,32)
__global__ __launch_bounds__(256) void transpose_k(const float* __restrict__ in,
                                                   short* __restrict__ out) {
  __shared__ float t[32][33];
  int tx = threadIdx.x, ty = threadIdx.y;
  int bx = blockIdx.x * 32, by = blockIdx.y * 32;
#pragma unroll
  for (int i = ty; i < 32; i += 8) t[i][tx] = in[(size_t)(by + i) * DMODEL + bx + tx];
  __syncthreads();
#pragma unroll
  for (int i = ty; i < 32; i += 8) out[(size_t)(bx + i) * DMODEL + by + tx] = f2bf(t[tx][i]);
}

// T5 relative position bias table: tab[h*2047 + (rel+1023)]
__global__ void bias_k(const float* __restrict__ rel_bias, float* __restrict__ tab) {
  int i = blockIdx.x * 256 + threadIdx.x;
  if (i >= NH * NB_TAB) return;
  int h = i / NB_TAB, j = i % NB_TAB;
  int rel = j - 1023;  // k - q
  int bucket = (rel > 0) ? 16 : 0;
  int r = rel < 0 ? -rel : rel;
  int b;
  if (r < 8) {
    b = r;
  } else {
    // 8 + trunc(log(r/8)/log(16) * 8), clamped to 15
    float lf = logf((float)r * 0.125f) * (8.0f / 2.772588722239781f);
    b = 8 + (int)lf;
    if (b > 15) b = 15;
  }
  bucket += b;
  tab[i] = rel_bias[bucket * NH + h];
}

// GEMM C[M,N] = A[M,K] * BT[N,K]^T, bf16 MFMA 16x16x32, fp32 accum.
// BM=128, BN=64, BK=32, 256 threads = 4 waves (2x2), each wave 64x32 (4x2 frags).
// AF32: A is fp32 (convert to bf16 at staging). EPI 0: scatter to Q/K/V bf16
// per-head layout; EPI 1: write fp32 Fo[M,1024].
template <int AF32, int EPI>
__global__ __launch_bounds__(256) void gemm_k(const void* __restrict__ Ap,
                                              const short* __restrict__ BT,
                                              short* __restrict__ Qo, short* __restrict__ Ko,
                                              short* __restrict__ Vo, float* __restrict__ Fo) {
  constexpr int K = DMODEL;
  __shared__ short lA[128 * 32];
  __shared__ short lB[64 * 32];
  int tid = threadIdx.x;
  int lane = tid & 63, wid = tid >> 6;
  int lane16 = lane & 15, kl = lane >> 4;
  int bm = blockIdx.y * 128, bn = blockIdx.x * 64;
  int wm = (wid & 1) * 64, wn = (wid >> 1) * 32;
  floatx4 acc[4][2] = {};
  const float* Af = (const float*)Ap;
  const short* Ab = (const short*)Ap;
  int ra = tid >> 1, ha = (tid & 1) * 16;  // A stage: 16 elems/thread
  int rb = tid >> 2, qb = (tid & 3) * 8;   // B stage: 8 elems/thread
  for (int k0 = 0; k0 < K; k0 += 32) {
    __syncthreads();
    if constexpr (AF32) {
      const floatx4* s4 = (const floatx4*)(Af + (size_t)(bm + ra) * K + k0 + ha);
      floatx4 f0 = s4[0], f1 = s4[1], f2 = s4[2], f3 = s4[3];
      short8v t0, t1;
#pragma unroll
      for (int j = 0; j < 4; ++j) {
        t0[j] = f2bf(f0[j]);
        t0[4 + j] = f2bf(f1[j]);
        t1[j] = f2bf(f2[j]);
        t1[4 + j] = f2bf(f3[j]);
      }
      *(short8v*)&lA[ra * 32 + ha] = t0;
      *(short8v*)&lA[ra * 32 + ha + 8] = t1;
    } else {
      const short8v* s8 = (const short8v*)(Ab + (size_t)(bm + ra) * K + k0 + ha);
      *(short8v*)&lA[ra * 32 + ha] = s8[0];
      *(short8v*)&lA[ra * 32 + ha + 8] = s8[1];
    }
    *(short8v*)&lB[rb * 32 + qb] = *(const short8v*)&BT[(size_t)(bn + rb) * K + k0 + qb];
    __syncthreads();
    short8v af[4], bf[2];
#pragma unroll
    for (int mt = 0; mt < 4; ++mt)
      af[mt] = *(const short8v*)&lA[(wm + mt * 16 + lane16) * 32 + kl * 8];
#pragma unroll
    for (int nt = 0; nt < 2; ++nt)
      bf[nt] = *(const short8v*)&lB[(wn + nt * 16 + lane16) * 32 + kl * 8];
#pragma unroll
    for (int mt = 0; mt < 4; ++mt)
#pragma unroll
      for (int nt = 0; nt < 2; ++nt)
        acc[mt][nt] = __builtin_amdgcn_mfma_f32_16x16x32_bf16(af[mt], bf[nt], acc[mt][nt], 0, 0, 0);
  }
  // C/D layout: col = lane&15, row = (lane>>4)*4 + reg  [measured m89]
#pragma unroll
  for (int mt = 0; mt < 4; ++mt)
#pragma unroll
    for (int nt = 0; nt < 2; ++nt)
#pragma unroll
      for (int r = 0; r < 4; ++r) {
        int gr = bm + wm + mt * 16 + kl * 4 + r;
        int gc = bn + wn + nt * 16 + lane16;
        float v = acc[mt][nt][r];
        if constexpr (EPI == 0) {
          int which = gc >> 10, rr = gc & 1023;
          int hh = rr >> 6, d = rr & 63;
          int bb = gr >> 10, s = gr & 1023;
          short* dst = which == 0 ? Qo : (which == 1 ? Ko : Vo);
          dst[(size_t)((((bb << 4) + hh) << 10) + s) * 64 + d] = f2bf(v);
        } else {
          Fo[(size_t)gr * DMODEL + gc] = v;
        }
      }
}

// Flash attention, bf16 MFMA. Block: (qt, bh), 256 thr = 4 waves, each wave 16 q-rows.
// KV tiles of 64 staged in LDS (V transposed at stage). Online softmax in fp32.
__global__ __launch_bounds__(256) void attn_k(const short* __restrict__ Q,
                                              const short* __restrict__ K,
                                              const short* __restrict__ V,
                                              const float* __restrict__ mask,
                                              const float* __restrict__ biasTab,
                                              short* __restrict__ O) {
  __shared__ short lK[64 * 64];
  __shared__ short lVt[64 * 72];      // Vt[d][kv], stride 72 keeps b128 aligned
  __shared__ short lP[4 * 16 * 72];   // per-wave P tile [16][64], stride 72
  __shared__ float lBias[NB_TAB];
  int tid = threadIdx.x;
  int lane = tid & 63, wid = tid >> 6;
  int lane16 = lane & 15, kl = lane >> 4;
  int qt = blockIdx.x, bh = blockIdx.y;
  int h = bh & 15, b = bh >> 4;
  for (int i = tid; i < NB_TAB; i += 256) lBias[i] = biasTab[h * NB_TAB + i];

  int qrow = qt * 64 + wid * 16 + lane16;
  const short8v* qbase = (const short8v*)(Q + ((size_t)bh * S_LEN + qrow) * DK);
  short8v qf0 = qbase[kl], qf1 = qbase[kl + 4];  // A-frag: row=lane%16, k=8*(lane/16)+j

  float m_[4], l_[4];
  floatx4 o[4] = {};
#pragma unroll
  for (int r = 0; r < 4; ++r) {
    m_[r] = -1e30f;
    l_[r] = 0.0f;
  }
  int qg0 = qt * 64 + wid * 16 + kl * 4;
  short* myP = &lP[wid * 16 * 72];

  for (int kv0 = 0; kv0 < S_LEN; kv0 += 64) {
    __syncthreads();  // prev iter's LDS reads done
    {
      int c0 = tid * 2;
#pragma unroll
      for (int u = 0; u < 2; ++u) {
        int cc = c0 + u;
        int r = cc >> 3, co = (cc & 7) * 8;
        *(short8v*)&lK[r * 64 + co] =
            *(const short8v*)&K[((size_t)bh * S_LEN + kv0 + r) * DK + co];
        short8v vv = *(const short8v*)&V[((size_t)bh * S_LEN + kv0 + r) * DK + co];
#pragma unroll
        for (int j = 0; j < 8; ++j) lVt[(co + j) * 72 + r] = vv[j];
      }
    }
    __syncthreads();
    // scores S = Q * K^T  (B-frag: col=lane%16 from lK rows = key positions)
    floatx4 sa[4] = {};
#pragma unroll
    for (int nt = 0; nt < 4; ++nt) {
      short8v kb0 = *(const short8v*)&lK[(nt * 16 + lane16) * 64 + kl * 8];
      short8v kb1 = *(const short8v*)&lK[(nt * 16 + lane16) * 64 + 32 + kl * 8];
      sa[nt] = __builtin_amdgcn_mfma_f32_16x16x32_bf16(qf0, kb0, sa[nt], 0, 0, 0);
      sa[nt] = __builtin_amdgcn_mfma_f32_16x16x32_bf16(qf1, kb1, sa[nt], 0, 0, 0);
    }
    // + rel-pos bias + mask
    float sv[4][4];
#pragma unroll
    for (int nt = 0; nt < 4; ++nt) {
      int kg = kv0 + nt * 16 + lane16;
#pragma unroll
      for (int r = 0; r < 4; ++r) {
        int qg = qg0 + r;
        sv[nt][r] = sa[nt][r] + lBias[kg - qg + 1023] + mask[(size_t)qg * S_LEN + kg];
      }
    }
    // online softmax: each q-row lives in a 16-lane group (lane>>4 fixed)
    float alpha[4];
#pragma unroll
    for (int r = 0; r < 4; ++r) {
      float mr = fmaxf(fmaxf(sv[0][r], sv[1][r]), fmaxf(sv[2][r], sv[3][r]));
      mr = fmaxf(mr, __shfl_xor(mr, 1));
      mr = fmaxf(mr, __shfl_xor(mr, 2));
      mr = fmaxf(mr, __shfl_xor(mr, 4));
      mr = fmaxf(mr, __shfl_xor(mr, 8));
      float mn = fmaxf(m_[r], mr);
      alpha[r] = __expf(m_[r] - mn);
      m_[r] = mn;
      float rs = 0.0f;
#pragma unroll
      for (int nt = 0; nt < 4; ++nt) {
        float pv = __expf(sv[nt][r] - mn);
        sv[nt][r] = pv;
        rs += pv;
      }
      rs += __shfl_xor(rs, 1);
      rs += __shfl_xor(rs, 2);
      rs += __shfl_xor(rs, 4);
      rs += __shfl_xor(rs, 8);
      l_[r] = l_[r] * alpha[r] + rs;
    }
#pragma unroll
    for (int dt = 0; dt < 4; ++dt)
#pragma unroll
      for (int r = 0; r < 4; ++r) o[dt][r] *= alpha[r];
    // P -> bf16 -> LDS (transpose from C-layout to A-frag layout)
#pragma unroll
    for (int nt = 0; nt < 4; ++nt)
#pragma unroll
      for (int r = 0; r < 4; ++r)
        myP[(kl * 4 + r) * 72 + nt * 16 + lane16] = f2bf(sv[nt][r]);
    __syncthreads();
    // O += P * V   (A-frag from myP rows, B-frag from Vt rows = d columns)
#pragma unroll
    for (int dt = 0; dt < 4; ++dt) {
#pragma unroll
      for (int k0 = 0; k0 < 2; ++k0) {
        short8v pa = *(const short8v*)&myP[lane16 * 72 + k0 * 32 + kl * 8];
        short8v vb = *(const short8v*)&lVt[(dt * 16 + lane16) * 72 + k0 * 32 + kl * 8];
        o[dt] = __builtin_amdgcn_mfma_f32_16x16x32_bf16(pa, vb, o[dt], 0, 0, 0);
      }
    }
  }
  // epilogue: O / l, write bf16 [B*S][H*DK]
#pragma unroll
  for (int dt = 0; dt < 4; ++dt)
#pragma unroll
    for (int r = 0; r < 4; ++r) {
      int qg = qg0 + r, dc = dt * 16 + lane16;
      float val = o[dt][r] / l_[r];
      O[((size_t)(b * S_LEN + qg)) * DMODEL + h * 64 + dc] = f2bf(val);
    }
}

extern "C" void kernel_launch(void* const* d_in, const int* in_sizes, int n_in, void* d_out,
                              int out_size, void* d_ws, size_t ws_size, hipStream_t stream) {
  (void)in_sizes;
  (void)n_in;
  (void)out_size;
  (void)ws_size;
  const float* hs = (const float*)d_in[0];
  const float* mask = (const float*)d_in[1];
  const float* wq = (const float*)d_in[2];
  const float* wk = (const float*)d_in[3];
  const float* wv = (const float*)d_in[4];
  const float* wo = (const float*)d_in[5];
  const float* relb = (const float*)d_in[6];
  float* out = (float*)d_out;
  char* ws = (char*)d_ws;
  // workspace layout (~40.2 MB)
  short* wT = (short*)(ws);                               // [3072][1024] bf16 (wq^T|wk^T|wv^T)
  short* wTo = (short*)(ws + (size_t)6 * 1024 * 1024);    // [1024][1024] bf16 wo^T
  short* Qb = (short*)(ws + (size_t)8 * 1024 * 1024);     // [64][1024][64] bf16
  short* Kb = (short*)(ws + (size_t)16 * 1024 * 1024);
  short* Vb = (short*)(ws + (size_t)24 * 1024 * 1024);
  short* Ob = (short*)(ws + (size_t)32 * 1024 * 1024);    // [4096][1024] bf16
  float* btab = (float*)(ws + (size_t)40 * 1024 * 1024);  // [16][2047] f32

  dim3 tb(32, 8), tg(32, 32);
  transpose_k<<<tg, tb, 0, stream>>>(wq, wT);
  transpose_k<<<tg, tb, 0, stream>>>(wk, wT + 1024 * 1024);
  transpose_k<<<tg, tb, 0, stream>>>(wv, wT + 2 * 1024 * 1024);
  transpose_k<<<tg, tb, 0, stream>>>(wo, wTo);
  bias_k<<<(NH * NB_TAB + 255) / 256, 256, 0, stream>>>(relb, btab);
  gemm_k<1, 0><<<dim3(3072 / 64, 4096 / 128), 256, 0, stream>>>(hs, wT, Qb, Kb, Vb, nullptr);
  attn_k<<<dim3(16, 64), 256, 0, stream>>>(Qb, Kb, Vb, mask, btab, Ob);
  gemm_k<0, 1><<<dim3(1024 / 64, 4096 / 128), 256, 0, stream>>>(Ob, wTo, nullptr, nullptr, nullptr,
                                                                out);
}

// Round 2
// 242.619 us; speedup vs baseline: 1.1624x; 1.1624x over previous
//
#include <hip/hip_runtime.h>

typedef __attribute__((ext_vector_type(8))) short short8v;
typedef __attribute__((ext_vector_type(4))) float floatx4;

#define S_LEN 1024
#define DMODEL 1024
#define NH 16
#define DK 64
#define NB_TAB 2047  // rel = k - q in [-1023, 1023]

__device__ __forceinline__ short f2bf(float f) {
  unsigned u = __builtin_bit_cast(unsigned, f);
  u += 0x7fffu + ((u >> 16) & 1u);  // RNE
  return (short)(u >> 16);
}

__device__ __forceinline__ void load16(const void* g, void* l) {
  __builtin_amdgcn_global_load_lds((const __attribute__((address_space(1))) unsigned*)g,
                                   (__attribute__((address_space(3))) unsigned*)l, 16, 0, 0);
}

// out[n][k] = bf16(in[k][n]), 1024x1024. block (32,8), grid (32,32)
__global__ __launch_bounds__(256) void transpose_k(const float* __restrict__ in,
                                                   short* __restrict__ out) {
  __shared__ float t[32][33];
  int tx = threadIdx.x, ty = threadIdx.y;
  int bx = blockIdx.x * 32, by = blockIdx.y * 32;
#pragma unroll
  for (int i = ty; i < 32; i += 8) t[i][tx] = in[(size_t)(by + i) * DMODEL + bx + tx];
  __syncthreads();
#pragma unroll
  for (int i = ty; i < 32; i += 8) out[(size_t)(bx + i) * DMODEL + by + tx] = f2bf(t[tx][i]);
}

// fp32 -> bf16 bulk convert, 8 elems/thread
__global__ __launch_bounds__(256) void cvt_k(const float* __restrict__ in,
                                             short* __restrict__ out) {
  size_t i = ((size_t)blockIdx.x * 256 + threadIdx.x) * 8;
  const floatx4* p = (const floatx4*)(in + i);
  floatx4 a = p[0], b = p[1];
  short8v o;
#pragma unroll
  for (int j = 0; j < 4; ++j) {
    o[j] = f2bf(a[j]);
    o[4 + j] = f2bf(b[j]);
  }
  *(short8v*)(out + i) = o;
}

// T5 relative position bias table: tab[h*2047 + (rel+1023)]
__global__ void bias_k(const float* __restrict__ rel_bias, float* __restrict__ tab) {
  int i = blockIdx.x * 256 + threadIdx.x;
  if (i >= NH * NB_TAB) return;
  int h = i / NB_TAB, j = i % NB_TAB;
  int rel = j - 1023;  // k - q
  int bucket = (rel > 0) ? 16 : 0;
  int r = rel < 0 ? -rel : rel;
  int b;
  if (r < 8) {
    b = r;
  } else {
    float lf = logf((float)r * 0.125f) * (8.0f / 2.772588722239781f);
    b = 8 + (int)lf;
    if (b > 15) b = 15;
  }
  bucket += b;
  tab[i] = rel_bias[bucket * NH + h];
}

// V[bh][s][d] -> Vt[bh][d][s], bf16. grid (4 s-chunks, 64 bh), block 256.
// LDS tile [64 d][256 s], 512B rows, 16B-slot XOR swizzle keyed by (d>>3)&7.
__global__ __launch_bounds__(256) void vtrans_k(const short* __restrict__ V,
                                                short* __restrict__ Vt) {
  __shared__ short t[64 * 256];
  int tid = threadIdx.x;
  int s0 = blockIdx.x * 256;
  int bh = blockIdx.y;
#pragma unroll
  for (int i = 0; i < 8; ++i) {
    int s = i * 32 + (tid >> 3);
    int slot = tid & 7;
    short8v vv = *(const short8v*)&V[(((size_t)bh * S_LEN) + s0 + s) * DK + slot * 8];
#pragma unroll
    for (int j = 0; j < 8; ++j) {
      int d = slot * 8 + j;
      *(short*)((char*)t + d * 512 + ((s * 2) ^ (((d >> 3) & 7) << 4))) = vv[j];
    }
  }
  __syncthreads();
#pragma unroll
  for (int i = 0; i < 8; ++i) {
    int d = i * 8 + (tid >> 5);
    int sl = tid & 31;
    short8v vv = *(const short8v*)((char*)t + d * 512 + ((sl * 16) ^ (((d >> 3) & 7) << 4)));
    *(short8v*)&Vt[(((size_t)bh * DK) + d) * S_LEN + s0 + sl * 8] = vv;
  }
}

// GEMM C[M,N] = A[M,K(=1024)] * BT[N,K]^T, bf16 in, fp32 acc.
// BM=BN=128, BK=64, 256 thr = 4 waves (2x2), wave tile 64x64 (4x4 frags).
// Staging: global_load_lds 16B with pre-swizzled source; LDS 128B rows,
// 16B-slot ^= (row&7) -> conflict-free ds_read_b128 frag reads.
// EPI 0: scatter bf16 to Q/K/V per-head [bh][s][64]; EPI 1: fp32 C[M][1024].
template <int EPI>
__global__ __launch_bounds__(256) void gemm2_k(const short* __restrict__ A,
                                               const short* __restrict__ BT,
                                               short* __restrict__ Qo, short* __restrict__ Ko,
                                               short* __restrict__ Vo, float* __restrict__ Fo) {
  constexpr int K = DMODEL;
  __shared__ short lA[128 * 64];
  __shared__ short lB[128 * 64];
  int tid = threadIdx.x;
  int lane = tid & 63, wid = tid >> 6;
  int lane16 = lane & 15, kl = lane >> 4;
  int bm = blockIdx.y * 128, bn = blockIdx.x * 128;
  int wm = (wid & 1) * 64, wn = (wid >> 1) * 64;
  floatx4 acc[4][4] = {};

  // per-thread staging source pointers (advance by k0*2 bytes each step)
  const char* gA[4];
  const char* gB[4];
  int slot = lane & 7;
#pragma unroll
  for (int it = 0; it < 4; ++it) {
    int row = it * 32 + wid * 8 + (lane >> 3);
    int sw = (slot * 16) ^ ((row & 7) << 4);
    gA[it] = (const char*)A + ((size_t)(bm + row) * K) * 2 + sw;
    gB[it] = (const char*)BT + ((size_t)(bn + row) * K) * 2 + sw;
  }

  for (int k0 = 0; k0 < K; k0 += 64) {
    __syncthreads();
#pragma unroll
    for (int it = 0; it < 4; ++it) {
      char* la = (char*)lA + (it * 32 + wid * 8) * 128;
      char* lb = (char*)lB + (it * 32 + wid * 8) * 128;
      load16(gA[it] + k0 * 2, la);
      load16(gB[it] + k0 * 2, lb);
    }
    __syncthreads();
#pragma unroll
    for (int kc = 0; kc < 2; ++kc) {
      short8v af[4], bf[4];
#pragma unroll
      for (int mt = 0; mt < 4; ++mt) {
        int row = wm + mt * 16 + lane16;
        af[mt] = *(const short8v*)((char*)lA + row * 128 +
                                   ((kc * 64 + kl * 16) ^ ((row & 7) << 4)));
      }
#pragma unroll
      for (int nt = 0; nt < 4; ++nt) {
        int row = wn + nt * 16 + lane16;
        bf[nt] = *(const short8v*)((char*)lB + row * 128 +
                                   ((kc * 64 + kl * 16) ^ ((row & 7) << 4)));
      }
#pragma unroll
      for (int mt = 0; mt < 4; ++mt)
#pragma unroll
        for (int nt = 0; nt < 4; ++nt)
          acc[mt][nt] =
              __builtin_amdgcn_mfma_f32_16x16x32_bf16(af[mt], bf[nt], acc[mt][nt], 0, 0, 0);
    }
  }
  // C/D layout: col = lane&15, row = (lane>>4)*4 + reg
  if constexpr (EPI == 0) {
    int which = bn >> 10;
    int gcb = bn & 1023;
    short* dst = which == 0 ? Qo : (which == 1 ? Ko : Vo);
#pragma unroll
    for (int mt = 0; mt < 4; ++mt)
#pragma unroll
      for (int nt = 0; nt < 4; ++nt)
#pragma unroll
        for (int r = 0; r < 4; ++r) {
          int gr = bm + wm + mt * 16 + kl * 4 + r;
          int gc = gcb + wn + nt * 16 + lane16;
          int hh = gc >> 6, d = gc & 63;
          int bb = gr >> 10, s = gr & 1023;
          dst[(size_t)((bb * 16 + hh) * 1024 + s) * 64 + d] = f2bf(acc[mt][nt][r]);
        }
  } else {
#pragma unroll
    for (int mt = 0; mt < 4; ++mt)
#pragma unroll
      for (int nt = 0; nt < 4; ++nt)
#pragma unroll
        for (int r = 0; r < 4; ++r) {
          int gr = bm + wm + mt * 16 + kl * 4 + r;
          int gc = bn + wn + nt * 16 + lane16;
          Fo[(size_t)gr * DMODEL + gc] = acc[mt][nt][r];
        }
  }
}

// Flash attention. Block (qt, bh), 256 thr = 4 waves, wave = 16 q-rows.
// K and Vt tiles staged via global_load_lds with pre-swizzled source;
// frag reads XOR-swizzled -> conflict-free.
__global__ __launch_bounds__(256) void attn_k(const short* __restrict__ Q,
                                              const short* __restrict__ Kg,
                                              const short* __restrict__ Vt,
                                              const float* __restrict__ mask,
                                              const float* __restrict__ biasTab,
                                              short* __restrict__ O) {
  __shared__ short lK[64 * 64];   // [kv][d], swizzled slots
  __shared__ short lVt[64 * 64];  // [d][kv], swizzled slots
  __shared__ short lP[4 * 16 * 72];
  __shared__ float lBias[NB_TAB];
  int tid = threadIdx.x;
  int lane = tid & 63, wid = tid >> 6;
  int lane16 = lane & 15, kl = lane >> 4;
  int qt = blockIdx.x, bh = blockIdx.y;
  int h = bh & 15, b = bh >> 4;
  for (int i = tid; i < NB_TAB; i += 256) lBias[i] = biasTab[h * NB_TAB + i];

  int qrow = qt * 64 + wid * 16 + lane16;
  const short8v* qbase = (const short8v*)(Q + ((size_t)bh * S_LEN + qrow) * DK);
  short8v qf0 = qbase[kl], qf1 = qbase[kl + 4];

  // staging source pointers (row&7 swizzle fixed per thread)
  int slot = lane & 7;
  const char* gK[2];
  const char* gV[2];
#pragma unroll
  for (int it = 0; it < 2; ++it) {
    int row = it * 32 + wid * 8 + (lane >> 3);
    int sw = (slot * 16) ^ ((row & 7) << 4);
    gK[it] = (const char*)Kg + ((size_t)(bh * S_LEN + row) * DK) * 2 + sw;  // +kv0*128/step
    gV[it] = (const char*)Vt + ((size_t)(bh * DK + row) * S_LEN) * 2 + sw;  // +kv0*2/step
  }

  float m_[4], l_[4];
  floatx4 o[4] = {};
#pragma unroll
  for (int r = 0; r < 4; ++r) {
    m_[r] = -1e30f;
    l_[r] = 0.0f;
  }
  int qg0 = qt * 64 + wid * 16 + kl * 4;
  short* myP = &lP[wid * 16 * 72];

  for (int kv0 = 0; kv0 < S_LEN; kv0 += 64) {
    __syncthreads();  // prev iter's LDS reads done
#pragma unroll
    for (int it = 0; it < 2; ++it) {
      char* lk = (char*)lK + (it * 32 + wid * 8) * 128;
      char* lv = (char*)lVt + (it * 32 + wid * 8) * 128;
      load16(gK[it] + (size_t)kv0 * 128, lk);
      load16(gV[it] + (size_t)kv0 * 2, lv);
    }
    __syncthreads();
    // S = Q K^T
    floatx4 sa[4] = {};
#pragma unroll
    for (int nt = 0; nt < 4; ++nt) {
      int row = nt * 16 + lane16;
      int sw = (row & 7) << 4;
      short8v kb0 = *(const short8v*)((char*)lK + row * 128 + ((kl * 16) ^ sw));
      short8v kb1 = *(const short8v*)((char*)lK + row * 128 + ((64 + kl * 16) ^ sw));
      sa[nt] = __builtin_amdgcn_mfma_f32_16x16x32_bf16(qf0, kb0, sa[nt], 0, 0, 0);
      sa[nt] = __builtin_amdgcn_mfma_f32_16x16x32_bf16(qf1, kb1, sa[nt], 0, 0, 0);
    }
    // + rel-pos bias + mask
    float sv[4][4];
#pragma unroll
    for (int nt = 0; nt < 4; ++nt) {
      int kg = kv0 + nt * 16 + lane16;
#pragma unroll
      for (int r = 0; r < 4; ++r) {
        int qg = qg0 + r;
        sv[nt][r] = sa[nt][r] + lBias[kg - qg + 1023] + mask[(size_t)qg * S_LEN + kg];
      }
    }
    // online softmax (q-row lives in a 16-lane group)
    float alpha[4];
#pragma unroll
    for (int r = 0; r < 4; ++r) {
      float mr = fmaxf(fmaxf(sv[0][r], sv[1][r]), fmaxf(sv[2][r], sv[3][r]));
      mr = fmaxf(mr, __shfl_xor(mr, 1));
      mr = fmaxf(mr, __shfl_xor(mr, 2));
      mr = fmaxf(mr, __shfl_xor(mr, 4));
      mr = fmaxf(mr, __shfl_xor(mr, 8));
      float mn = fmaxf(m_[r], mr);
      alpha[r] = __expf(m_[r] - mn);
      m_[r] = mn;
      float rs = 0.0f;
#pragma unroll
      for (int nt = 0; nt < 4; ++nt) {
        float pv = __expf(sv[nt][r] - mn);
        sv[nt][r] = pv;
        rs += pv;
      }
      rs += __shfl_xor(rs, 1);
      rs += __shfl_xor(rs, 2);
      rs += __shfl_xor(rs, 4);
      rs += __shfl_xor(rs, 8);
      l_[r] = l_[r] * alpha[r] + rs;
    }
#pragma unroll
    for (int dt = 0; dt < 4; ++dt)
#pragma unroll
      for (int r = 0; r < 4; ++r) o[dt][r] *= alpha[r];
    // P -> bf16 -> LDS (C-layout -> A-frag layout)
#pragma unroll
    for (int nt = 0; nt < 4; ++nt)
#pragma unroll
      for (int r = 0; r < 4; ++r)
        myP[(kl * 4 + r) * 72 + nt * 16 + lane16] = f2bf(sv[nt][r]);
    __syncthreads();
    // O += P * V
    short8v pa0 = *(const short8v*)((char*)myP + lane16 * 144 + kl * 16);
    short8v pa1 = *(const short8v*)((char*)myP + lane16 * 144 + 64 + kl * 16);
#pragma unroll
    for (int dt = 0; dt < 4; ++dt) {
      int row = dt * 16 + lane16;
      int sw = (row & 7) << 4;
      short8v vb0 = *(const short8v*)((char*)lVt + row * 128 + ((kl * 16) ^ sw));
      short8v vb1 = *(const short8v*)((char*)lVt + row * 128 + ((64 + kl * 16) ^ sw));
      o[dt] = __builtin_amdgcn_mfma_f32_16x16x32_bf16(pa0, vb0, o[dt], 0, 0, 0);
      o[dt] = __builtin_amdgcn_mfma_f32_16x16x32_bf16(pa1, vb1, o[dt], 0, 0, 0);
    }
  }
  // epilogue: O / l, write bf16 [B*S][H*DK]
#pragma unroll
  for (int dt = 0; dt < 4; ++dt)
#pragma unroll
    for (int r = 0; r < 4; ++r) {
      int qg = qg0 + r, dc = dt * 16 + lane16;
      float val = o[dt][r] / l_[r];
      O[((size_t)(b * S_LEN + qg)) * DMODEL + h * 64 + dc] = f2bf(val);
    }
}

extern "C" void kernel_launch(void* const* d_in, const int* in_sizes, int n_in, void* d_out,
                              int out_size, void* d_ws, size_t ws_size, hipStream_t stream) {
  (void)in_sizes;
  (void)n_in;
  (void)out_size;
  (void)ws_size;
  const float* hs = (const float*)d_in[0];
  const float* mask = (const float*)d_in[1];
  const float* wq = (const float*)d_in[2];
  const float* wk = (const float*)d_in[3];
  const float* wv = (const float*)d_in[4];
  const float* wo = (const float*)d_in[5];
  const float* relb = (const float*)d_in[6];
  float* out = (float*)d_out;
  char* ws = (char*)d_ws;
  const size_t MB = 1024 * 1024;
  short* wT = (short*)(ws);                  // [3072][1024] bf16
  short* wTo = (short*)(ws + 6 * MB);        // [1024][1024] bf16
  short* Ab = (short*)(ws + 8 * MB);         // [4096][1024] bf16 (hs); reused as Ob
  short* Qb = (short*)(ws + 16 * MB);        // [64][1024][64] bf16
  short* Kb = (short*)(ws + 24 * MB);
  short* Vb = (short*)(ws + 32 * MB);
  short* Vtb = (short*)(ws + 40 * MB);       // [64][64][1024] bf16
  float* btab = (float*)(ws + 48 * MB);      // [16][2047] f32
  short* Ob = Ab;

  dim3 tb(32, 8), tg(32, 32);
  transpose_k<<<tg, tb, 0, stream>>>(wq, wT);
  transpose_k<<<tg, tb, 0, stream>>>(wk, wT + 1024 * 1024);
  transpose_k<<<tg, tb, 0, stream>>>(wv, wT + 2 * 1024 * 1024);
  transpose_k<<<tg, tb, 0, stream>>>(wo, wTo);
  bias_k<<<(NH * NB_TAB + 255) / 256, 256, 0, stream>>>(relb, btab);
  cvt_k<<<4096 * 1024 / 8 / 256, 256, 0, stream>>>(hs, Ab);
  gemm2_k<0><<<dim3(3072 / 128, 4096 / 128), 256, 0, stream>>>(Ab, wT, Qb, Kb, Vb, nullptr);
  vtrans_k<<<dim3(4, 64), 256, 0, stream>>>(Vb, Vtb);
  attn_k<<<dim3(16, 64), 256, 0, stream>>>(Qb, Kb, Vtb, mask, btab, Ob);
  gemm2_k<1><<<dim3(1024 / 128, 4096 / 128), 256, 0, stream>>>(Ob, wTo, nullptr, nullptr, nullptr,
                                                               out);
}

// Round 4
// 205.601 us; speedup vs baseline: 1.3717x; 1.1800x over previous
//
#include <hip/hip_runtime.h>

typedef __attribute__((ext_vector_type(8))) short short8v;
typedef __attribute__((ext_vector_type(4))) short short4v;
typedef __attribute__((ext_vector_type(4))) float floatx4;
typedef __attribute__((ext_vector_type(16))) float f32x16;
typedef __attribute__((ext_vector_type(4))) unsigned uint4v;
typedef __attribute__((ext_vector_type(2))) unsigned uint2v;

#define S_LEN 1024
#define DMODEL 1024
#define NH 16
#define DK 64
#define NB_TAB 2047  // rel = k - q in [-1023, 1023]

__device__ __forceinline__ short f2bf(float f) {
  unsigned u = __builtin_bit_cast(unsigned, f);
  u += 0x7fffu + ((u >> 16) & 1u);  // RNE
  return (short)(u >> 16);
}

__device__ __forceinline__ unsigned cvtpk(float lo, float hi) {
  unsigned r;
  asm("v_cvt_pk_bf16_f32 %0, %1, %2" : "=v"(r) : "v"(lo), "v"(hi));
  return r;
}

__device__ __forceinline__ void pswap(unsigned& x, unsigned& y) {
  asm volatile("v_permlane32_swap_b32 %0, %1" : "+v"(x), "+v"(y));
}

__device__ __forceinline__ void load16(const void* g, void* l) {
  __builtin_amdgcn_global_load_lds((const __attribute__((address_space(1))) unsigned*)g,
                                   (__attribute__((address_space(3))) unsigned*)l, 16, 0, 0);
}

// 4 weight transposes in one launch: z<3 -> wT + z*1M (wq,wk,wv), z=3 -> wTo (wo)
__global__ __launch_bounds__(256) void transpose4_k(const float* __restrict__ wq,
                                                    const float* __restrict__ wk,
                                                    const float* __restrict__ wv,
                                                    const float* __restrict__ wo,
                                                    short* __restrict__ wT,
                                                    short* __restrict__ wTo) {
  __shared__ float t[32][33];
  int z = blockIdx.z;
  const float* in = z == 0 ? wq : (z == 1 ? wk : (z == 2 ? wv : wo));
  short* out = z < 3 ? wT + (size_t)z * 1024 * 1024 : wTo;
  int tx = threadIdx.x, ty = threadIdx.y;
  int bx = blockIdx.x * 32, by = blockIdx.y * 32;
#pragma unroll
  for (int i = ty; i < 32; i += 8) t[i][tx] = in[(size_t)(by + i) * DMODEL + bx + tx];
  __syncthreads();
#pragma unroll
  for (int i = ty; i < 32; i += 8) out[(size_t)(bx + i) * DMODEL + by + tx] = f2bf(t[tx][i]);
}

// fp32 -> bf16 bulk convert, 8 elems/thread
__global__ __launch_bounds__(256) void cvt_k(const float* __restrict__ in,
                                             short* __restrict__ out) {
  size_t i = ((size_t)blockIdx.x * 256 + threadIdx.x) * 8;
  const floatx4* p = (const floatx4*)(in + i);
  floatx4 a = p[0], b = p[1];
  short8v o;
#pragma unroll
  for (int j = 0; j < 4; ++j) {
    o[j] = f2bf(a[j]);
    o[4 + j] = f2bf(b[j]);
  }
  *(short8v*)(out + i) = o;
}

// T5 relative position bias table: tab[h*2047 + (rel+1023)]
__global__ void bias_k(const float* __restrict__ rel_bias, float* __restrict__ tab) {
  int i = blockIdx.x * 256 + threadIdx.x;
  if (i >= NH * NB_TAB) return;
  int h = i / NB_TAB, j = i % NB_TAB;
  int rel = j - 1023;  // k - q
  int bucket = (rel > 0) ? 16 : 0;
  int r = rel < 0 ? -rel : rel;
  int b;
  if (r < 8) {
    b = r;
  } else {
    float lf = logf((float)r * 0.125f) * (8.0f / 2.772588722239781f);
    b = 8 + (int)lf;
    if (b > 15) b = 15;
  }
  bucket += b;
  tab[i] = rel_bias[bucket * NH + h];
}

// V[bh][s][d] -> Vt[bh][d][s], bf16. grid (4 s-chunks, 64 bh), block 256.
__global__ __launch_bounds__(256) void vtrans_k(const short* __restrict__ V,
                                                short* __restrict__ Vt) {
  __shared__ short t[64 * 256];
  int tid = threadIdx.x;
  int s0 = blockIdx.x * 256;
  int bh = blockIdx.y;
#pragma unroll
  for (int i = 0; i < 8; ++i) {
    int s = i * 32 + (tid >> 3);
    int slot = tid & 7;
    short8v vv = *(const short8v*)&V[(((size_t)bh * S_LEN) + s0 + s) * DK + slot * 8];
#pragma unroll
    for (int j = 0; j < 8; ++j) {
      int d = slot * 8 + j;
      *(short*)((char*)t + d * 512 + ((s * 2) ^ (((d >> 3) & 7) << 4))) = vv[j];
    }
  }
  __syncthreads();
#pragma unroll
  for (int i = 0; i < 8; ++i) {
    int d = i * 8 + (tid >> 5);
    int sl = tid & 31;
    short8v vv = *(const short8v*)((char*)t + d * 512 + ((sl * 16) ^ (((d >> 3) & 7) << 4)));
    *(short8v*)&Vt[(((size_t)bh * DK) + d) * S_LEN + s0 + sl * 8] = vv;
  }
}

// GEMM C[M,N] = A[M,K(=1024)] * BT[N,K]^T, bf16 in, fp32 acc. (unchanged from r2)
template <int EPI>
__global__ __launch_bounds__(256) void gemm2_k(const short* __restrict__ A,
                                               const short* __restrict__ BT,
                                               short* __restrict__ Qo, short* __restrict__ Ko,
                                               short* __restrict__ Vo, float* __restrict__ Fo) {
  constexpr int K = DMODEL;
  __shared__ short lA[128 * 64];
  __shared__ short lB[128 * 64];
  int tid = threadIdx.x;
  int lane = tid & 63, wid = tid >> 6;
  int lane16 = lane & 15, kl = lane >> 4;
  int bm = blockIdx.y * 128, bn = blockIdx.x * 128;
  int wm = (wid & 1) * 64, wn = (wid >> 1) * 64;
  floatx4 acc[4][4] = {};

  const char* gA[4];
  const char* gB[4];
  int slot = lane & 7;
#pragma unroll
  for (int it = 0; it < 4; ++it) {
    int row = it * 32 + wid * 8 + (lane >> 3);
    int sw = (slot * 16) ^ ((row & 7) << 4);
    gA[it] = (const char*)A + ((size_t)(bm + row) * K) * 2 + sw;
    gB[it] = (const char*)BT + ((size_t)(bn + row) * K) * 2 + sw;
  }

  for (int k0 = 0; k0 < K; k0 += 64) {
    __syncthreads();
#pragma unroll
    for (int it = 0; it < 4; ++it) {
      char* la = (char*)lA + (it * 32 + wid * 8) * 128;
      char* lb = (char*)lB + (it * 32 + wid * 8) * 128;
      load16(gA[it] + k0 * 2, la);
      load16(gB[it] + k0 * 2, lb);
    }
    __syncthreads();
#pragma unroll
    for (int kc = 0; kc < 2; ++kc) {
      short8v af[4], bf[4];
#pragma unroll
      for (int mt = 0; mt < 4; ++mt) {
        int row = wm + mt * 16 + lane16;
        af[mt] = *(const short8v*)((char*)lA + row * 128 +
                                   ((kc * 64 + kl * 16) ^ ((row & 7) << 4)));
      }
#pragma unroll
      for (int nt = 0; nt < 4; ++nt) {
        int row = wn + nt * 16 + lane16;
        bf[nt] = *(const short8v*)((char*)lB + row * 128 +
                                   ((kc * 64 + kl * 16) ^ ((row & 7) << 4)));
      }
#pragma unroll
      for (int mt = 0; mt < 4; ++mt)
#pragma unroll
        for (int nt = 0; nt < 4; ++nt)
          acc[mt][nt] =
              __builtin_amdgcn_mfma_f32_16x16x32_bf16(af[mt], bf[nt], acc[mt][nt], 0, 0, 0);
    }
  }
  if constexpr (EPI == 0) {
    int which = bn >> 10;
    int gcb = bn & 1023;
    short* dst = which == 0 ? Qo : (which == 1 ? Ko : Vo);
#pragma unroll
    for (int mt = 0; mt < 4; ++mt)
#pragma unroll
      for (int nt = 0; nt < 4; ++nt)
#pragma unroll
        for (int r = 0; r < 4; ++r) {
          int gr = bm + wm + mt * 16 + kl * 4 + r;
          int gc = gcb + wn + nt * 16 + lane16;
          int hh = gc >> 6, d = gc & 63;
          int bb = gr >> 10, s = gr & 1023;
          dst[(size_t)((bb * 16 + hh) * 1024 + s) * 64 + d] = f2bf(acc[mt][nt][r]);
        }
  } else {
#pragma unroll
    for (int mt = 0; mt < 4; ++mt)
#pragma unroll
      for (int nt = 0; nt < 4; ++nt)
#pragma unroll
        for (int r = 0; r < 4; ++r) {
          int gr = bm + wm + mt * 16 + kl * 4 + r;
          int gc = bn + wn + nt * 16 + lane16;
          Fo[(size_t)gr * DMODEL + gc] = acc[mt][nt][r];
        }
  }
}

// Flash attention, m214-style. 4 waves x 32 q-rows = 128 q/block. Grid (8 qt, 64 bh).
// Swapped QK^T (32x32x16): S^T = mfma(K, Q^T) -> q on lane axis (col=lane&31),
// kv on reg axis. Softmax lane-local (+1 shfl_xor(32)). P->PV via cvt_pk +
// permlane32_swap. PV: O^T = mfma(V^T, P^T), q stays lane-local.
// K/Vt tiles (64 kv) double-buffered in LDS via global_load_lds, 1 barrier/iter.
__global__ __launch_bounds__(256) void attn32_k(const short* __restrict__ Q,
                                                const short* __restrict__ Kg,
                                                const short* __restrict__ Vt,
                                                const float* __restrict__ mask,
                                                const float* __restrict__ biasTab,
                                                short* __restrict__ O) {
  __shared__ short lK[2][64 * 64];  // [buf][kv][d], 16B-slot swizzled
  __shared__ short lV[2][64 * 64];  // [buf][d][kv], 16B-slot swizzled
  __shared__ float lBias[NB_TAB + 1];
  int tid = threadIdx.x;
  int lane = tid & 63, wid = tid >> 6;
  int l31 = lane & 31, L = lane >> 5;
  int qt = blockIdx.x, bh = blockIdx.y;
  int h = bh & 15, b = bh >> 4;

  int q = qt * 128 + wid * 32 + l31;  // this lane's q (stays on lane axis throughout)

  // staging pointers: per-wave contiguous 1KB chunks, inverse-swizzled source (G21)
  const char* gK[2];
  const char* gV[2];
  int ldst[2];
  {
    int slot = lane & 7;
#pragma unroll
    for (int i = 0; i < 2; ++i) {
      int row = i * 32 + wid * 8 + (lane >> 3);
      int ss = slot ^ ((row ^ (row >> 3)) & 7);
      gK[i] = (const char*)Kg + ((size_t)(bh * S_LEN + row) * DK + ss * 8) * 2;   // +kv0*128
      gV[i] = (const char*)Vt + ((size_t)(bh * DK + row) * S_LEN + ss * 8) * 2;   // +kv0*2
      ldst[i] = (i * 32 + wid * 8) * 128;
    }
  }
  // prologue: stage tile 0, fill bias LDS, load Q frags
#pragma unroll
  for (int i = 0; i < 2; ++i) {
    load16(gK[i], (char*)lK[0] + ldst[i]);
    load16(gV[i], (char*)lV[0] + ldst[i]);
  }
  for (int i = tid; i < NB_TAB; i += 256) lBias[i] = biasTab[h * NB_TAB + i];
  // Q B-frags: col=lane&31=q, k = ds*16 + L*8 + j
  const short8v* qp = (const short8v*)(Q + ((size_t)bh * S_LEN + q) * DK);
  short8v qf[4];
#pragma unroll
  for (int ds = 0; ds < 4; ++ds) qf[ds] = qp[ds * 2 + L];

  f32x16 ot[2] = {};  // O^T: ot[dt] rows d = dt*32+(reg&3)+8*(reg>>2)+4L, col q
  float m_ = -1e30f, l_ = 0.0f;
  __syncthreads();

  for (int it = 0; it < 16; ++it) {
    int kv0 = it * 64;
    int cur = it & 1;
    // mask loads, issued early (fp32 [q][kv], 4-consec kv groups)
    floatx4 mv[2][4];
#pragma unroll
    for (int hh = 0; hh < 2; ++hh)
#pragma unroll
      for (int g = 0; g < 4; ++g)
        mv[hh][g] = *(const floatx4*)(mask + (size_t)q * S_LEN + kv0 + hh * 32 + 8 * g + 4 * L);
    // stage next tile into other buffer
    if (it < 15) {
#pragma unroll
      for (int i = 0; i < 2; ++i) {
        load16(gK[i] + (size_t)(kv0 + 64) * 128, (char*)lK[cur ^ 1] + ldst[i]);
        load16(gV[i] + (size_t)(kv0 + 64) * 2, (char*)lV[cur ^ 1] + ldst[i]);
      }
    }
    // S^T = K * Q^T : A = K rows (kv), B = Q^T cols (q). C: col=q, row=kv.
    f32x16 sA[2];
#pragma unroll
    for (int hh = 0; hh < 2; ++hh) {
      f32x16 acc = {};
#pragma unroll
      for (int ds = 0; ds < 4; ++ds) {
        int row = hh * 32 + l31;
        int sw = ((row ^ (row >> 3)) & 7) << 4;
        short8v kf =
            *(const short8v*)((const char*)lK[cur] + row * 128 + ((ds * 32 + L * 16) ^ sw));
        acc = __builtin_amdgcn_mfma_f32_32x32x16_bf16(kf, qf[ds], acc, 0, 0, 0);
      }
      sA[hh] = acc;
    }
    // scores + bias + mask; kv(reg) = hh*32 + (reg&3) + 8*(reg>>2) + 4L
    float p[2][16];
#pragma unroll
    for (int hh = 0; hh < 2; ++hh)
#pragma unroll
      for (int g = 0; g < 4; ++g) {
        int bi = kv0 + hh * 32 + 8 * g + 4 * L - q + 1023;
        floatx4 mvv = mv[hh][g];
#pragma unroll
        for (int r3 = 0; r3 < 4; ++r3)
          p[hh][4 * g + r3] = sA[hh][4 * g + r3] + lBias[bi + r3] + mvv[r3];
      }
    // online softmax, lane-local q; one cross-half exchange
    float pmax = p[0][0];
#pragma unroll
    for (int hh = 0; hh < 2; ++hh)
#pragma unroll
      for (int r = 0; r < 16; ++r) pmax = fmaxf(pmax, p[hh][r]);
    pmax = fmaxf(pmax, __shfl_xor(pmax, 32));
    if (__any(pmax > m_ + 8.0f)) {  // defer-max (T13)
      float mn = fmaxf(m_, pmax);
      float al = __expf(m_ - mn);
      m_ = mn;
      l_ *= al;
#pragma unroll
      for (int dt = 0; dt < 2; ++dt) ot[dt] *= al;
    }
    float s = 0.0f;
#pragma unroll
    for (int hh = 0; hh < 2; ++hh)
#pragma unroll
      for (int r = 0; r < 16; ++r) {
        float e = __expf(p[hh][r] - m_);
        p[hh][r] = e;
        s += e;
      }
    s += __shfl_xor(s, 32);
    l_ += s;
    // P^T B-frags via cvt_pk + permlane32_swap, then O^T += V^T * P^T
#pragma unroll
    for (int ks = 0; ks < 4; ++ks) {
      const int hh = ks >> 1, bq = (ks & 1) * 8;
      unsigned A0 = cvtpk(p[hh][bq + 0], p[hh][bq + 1]);
      unsigned A1 = cvtpk(p[hh][bq + 2], p[hh][bq + 3]);
      unsigned B0 = cvtpk(p[hh][bq + 4], p[hh][bq + 5]);
      unsigned B1 = cvtpk(p[hh][bq + 6], p[hh][bq + 7]);
      pswap(A0, B0);
      pswap(A1, B1);
      uint4v uu = {A0, A1, B0, B1};
      short8v pf = __builtin_bit_cast(short8v, uu);
#pragma unroll
      for (int dt = 0; dt < 2; ++dt) {
        int row = dt * 32 + l31;
        int sw = ((row ^ (row >> 3)) & 7) << 4;
        short8v vf =
            *(const short8v*)((const char*)lV[cur] + row * 128 + ((ks * 32 + L * 16) ^ sw));
        ot[dt] = __builtin_amdgcn_mfma_f32_32x32x16_bf16(vf, pf, ot[dt], 0, 0, 0);
      }
    }
    __syncthreads();  // staged next-tile done (vmcnt drain) + all reads of cur done
  }
  // epilogue: O = O^T / l, write bf16 [b*S+q][h*64+d]
  float inv = 1.0f / l_;
  short* ob = O + ((size_t)(b * S_LEN + q)) * DMODEL + h * 64;
#pragma unroll
  for (int dt = 0; dt < 2; ++dt)
#pragma unroll
    for (int g = 0; g < 4; ++g) {
      int d0 = dt * 32 + 8 * g + 4 * L;
      uint2v w = {cvtpk(ot[dt][4 * g + 0] * inv, ot[dt][4 * g + 1] * inv),
                  cvtpk(ot[dt][4 * g + 2] * inv, ot[dt][4 * g + 3] * inv)};
      *(uint2v*)(ob + d0) = w;
    }
}

extern "C" void kernel_launch(void* const* d_in, const int* in_sizes, int n_in, void* d_out,
                              int out_size, void* d_ws, size_t ws_size, hipStream_t stream) {
  (void)in_sizes;
  (void)n_in;
  (void)out_size;
  (void)ws_size;
  const float* hs = (const float*)d_in[0];
  const float* mask = (const float*)d_in[1];
  const float* wq = (const float*)d_in[2];
  const float* wk = (const float*)d_in[3];
  const float* wv = (const float*)d_in[4];
  const float* wo = (const float*)d_in[5];
  const float* relb = (const float*)d_in[6];
  float* out = (float*)d_out;
  char* ws = (char*)d_ws;
  const size_t MB = 1024 * 1024;
  short* wT = (short*)(ws);              // [3072][1024] bf16
  short* wTo = (short*)(ws + 6 * MB);    // [1024][1024] bf16
  short* Ab = (short*)(ws + 8 * MB);     // [4096][1024] bf16 (hs); reused as Ob
  short* Qb = (short*)(ws + 16 * MB);    // [64][1024][64] bf16
  short* Kb = (short*)(ws + 24 * MB);
  short* Vb = (short*)(ws + 32 * MB);
  short* Vtb = (short*)(ws + 40 * MB);   // [64][64][1024] bf16
  float* btab = (float*)(ws + 48 * MB);  // [16][2047] f32
  short* Ob = Ab;

  transpose4_k<<<dim3(32, 32, 4), dim3(32, 8), 0, stream>>>(wq, wk, wv, wo, wT, wTo);
  bias_k<<<(NH * NB_TAB + 255) / 256, 256, 0, stream>>>(relb, btab);
  cvt_k<<<4096 * 1024 / 8 / 256, 256, 0, stream>>>(hs, Ab);
  gemm2_k<0><<<dim3(3072 / 128, 4096 / 128), 256, 0, stream>>>(Ab, wT, Qb, Kb, Vb, nullptr);
  vtrans_k<<<dim3(4, 64), 256, 0, stream>>>(Vb, Vtb);
  attn32_k<<<dim3(8, 64), 256, 0, stream>>>(Qb, Kb, Vtb, mask, btab, Ob);
  gemm2_k<1><<<dim3(1024 / 128, 4096 / 128), 256, 0, stream>>>(Ob, wTo, nullptr, nullptr, nullptr,
                                                               out);
}